// Round 8
// baseline (1506.684 us; speedup 1.0000x reference)
//
#include <hip/hip_runtime.h>

#define N_NODES 50000
#define E_ADJ   800000
#define E_DEC   200000
#define FDIM    128
#define HDIM    64
#define NP1     (N_NODES + 1)
#define SCAN_NB 196            // ceil(50000/256)

// ---- non-temporal helpers (streaming data: don't pollute L2) ----
__device__ __forceinline__ int   ntl_i(const int* p)   { return __builtin_nontemporal_load(p); }
__device__ __forceinline__ float ntl_f(const float* p) { return __builtin_nontemporal_load(p); }
__device__ __forceinline__ float2 ntl_f2(const float2* p) {
    unsigned long long v = __builtin_nontemporal_load((const unsigned long long*)p);
    float2 r;
    r.x = __int_as_float((int)(unsigned)(v & 0xffffffffull));
    r.y = __int_as_float((int)(unsigned)(v >> 32));
    return r;
}
__device__ __forceinline__ void nts_f(float* p, float v) { __builtin_nontemporal_store(v, p); }

// ---------------------------------------------------------------------------
// CSR build: histogram -> 3-phase exclusive scan -> scatter (counting sort)
// ---------------------------------------------------------------------------
__global__ void hist_kernel(const int* __restrict__ rows, int* __restrict__ counts)
{
    const int k = blockIdx.y;
    const int e = blockIdx.x * 256 + threadIdx.x;   // grid.x*256 == E_ADJ exactly
    const int r = ntl_i(&rows[(size_t)k * E_ADJ + e]);
    atomicAdd(&counts[k * N_NODES + r], 1);
}

__global__ void scan1(const int* __restrict__ counts,
                      int* __restrict__ row_ptr, int* __restrict__ blksums)
{
    const int k = blockIdx.y, b = blockIdx.x, tid = threadIdx.x;
    const int idx = b * 256 + tid;
    const int v = (idx < N_NODES) ? counts[k * N_NODES + idx] : 0;
    __shared__ int s[256];
    s[tid] = v;
    __syncthreads();
    for (int off = 1; off < 256; off <<= 1) {
        int t = (tid >= off) ? s[tid - off] : 0;
        __syncthreads();
        s[tid] += t;
        __syncthreads();
    }
    if (idx < N_NODES) row_ptr[k * NP1 + idx] = s[tid] - v;   // block-local exclusive
    if (tid == 255) blksums[k * SCAN_NB + b] = s[255];
}

__global__ void scan2(int* __restrict__ blksums)   // 1 block, 256 threads
{
    const int wave = threadIdx.x >> 6, lane = threadIdx.x & 63;
    if (wave < 4 && lane == 0) {
        int run = 0;
        for (int b = 0; b < SCAN_NB; ++b) {
            const int t = blksums[wave * SCAN_NB + b];
            blksums[wave * SCAN_NB + b] = run;
            run += t;
        }
    }
}

__global__ void scan3(int* __restrict__ row_ptr, const int* __restrict__ blksums,
                      int* __restrict__ wcur)
{
    const int k = blockIdx.y, b = blockIdx.x;
    const int idx = b * 256 + threadIdx.x;
    if (idx < N_NODES) {
        const int v = row_ptr[k * NP1 + idx] + blksums[k * SCAN_NB + b];
        row_ptr[k * NP1 + idx] = v;
        wcur[k * N_NODES + idx] = v;
    }
    if (idx == 0) row_ptr[k * NP1 + N_NODES] = E_ADJ;
}

// Streaming reads are NT so the scattered srt write-lines stay L2-resident and
// accumulate all 8 sub-line writes before writeback (kills 8x write-amp).
__global__ void scatter_kernel(const int* __restrict__ rows,
                               const int* __restrict__ cols,
                               const float* __restrict__ vals,
                               int* __restrict__ wcur, float2* __restrict__ srt)
{
    const int k = blockIdx.y;
    const int e = blockIdx.x * 256 + threadIdx.x;
    const int r = ntl_i(&rows[(size_t)k * E_ADJ + e]);
    const int c = ntl_i(&cols[(size_t)k * E_ADJ + e]);
    const float v = ntl_f(&vals[(size_t)k * E_ADJ + e]);
    const int pos = atomicAdd(&wcur[k * N_NODES + r], 1);
    srt[(size_t)k * E_ADJ + pos] = make_float2(__int_as_float(c), v);
}

// ---------------------------------------------------------------------------
// Stage-1 dense transform: xw[k][n][h] = sum_f xin_k[n][f] * W[k][f][h]
// ---------------------------------------------------------------------------
template <int FIN>
__global__ void gemm_stage(const float* __restrict__ x0,
                           const float* __restrict__ x1,
                           const float* __restrict__ W,   // [4][FIN][HDIM]
                           float* __restrict__ xw)        // [4][N][HDIM]
{
    const int wave = threadIdx.x >> 6;   // relation k
    const int lane = threadIdx.x & 63;   // h
    const int n0 = blockIdx.x * 8;       // 6250 blocks * 8 = 50000 exactly

    __shared__ float sx[2][8][FIN];
    for (int i = threadIdx.x; i < 8 * FIN; i += 256) {
        const int r = i / FIN, f = i % FIN;
        sx[0][r][f] = ntl_f(&x0[(size_t)(n0 + r) * FIN + f]);
        sx[1][r][f] = ntl_f(&x1[(size_t)(n0 + r) * FIN + f]);
    }
    __syncthreads();

    const float* Wk = W + (size_t)wave * FIN * HDIM;
    const float (*xr)[FIN] = sx[wave & 1];

    float acc[8] = {0.f, 0.f, 0.f, 0.f, 0.f, 0.f, 0.f, 0.f};
#pragma unroll 4
    for (int f = 0; f < FIN; ++f) {
        const float w = Wk[(size_t)f * HDIM + lane];
#pragma unroll
        for (int r = 0; r < 8; ++r)
            acc[r] = fmaf(xr[r][f], w, acc[r]);
    }

    float* outp = xw + ((size_t)wave * N_NODES + n0) * HDIM + lane;
#pragma unroll
    for (int r = 0; r < 8; ++r)
        outp[(size_t)r * HDIM] = acc[r];
}

// ---------------------------------------------------------------------------
// Stage-1 SPMM (post-transform gather) + relu + pairwise sum.
// ---------------------------------------------------------------------------
__global__ void spmm_csr(const float2* __restrict__ srt,    // [4][E] {col,val}
                         const int*    __restrict__ row_ptr,// [4][N+1]
                         const float*  __restrict__ xw,     // [4][N][H]
                         float* __restrict__ h0, float* __restrict__ h1)
{
    const int k = threadIdx.x >> 6;
    const int lane = threadIdx.x & 63;
    const int n = blockIdx.x;

    const int s  = row_ptr[k * NP1 + n];
    const int en = row_ptr[k * NP1 + n + 1];
    const float2* sp = srt + (size_t)k * E_ADJ;
    const float*  xk = xw + (size_t)k * N_NODES * HDIM;

    float a[8] = {0.f, 0.f, 0.f, 0.f, 0.f, 0.f, 0.f, 0.f};

    for (int base = s; base < en; base += 64) {
        const int cnt = min(64, en - base);
        float2 meta = make_float2(0.f, 0.f);
        if (lane < cnt) meta = ntl_f2(&sp[base + lane]);   // NT: streaming

        int j = 0;
        for (; j + 8 <= cnt; j += 8) {
            int   c[8];
            float v[8], g[8];
#pragma unroll
            for (int u = 0; u < 8; ++u) {
                c[u] = __shfl(__float_as_int(meta.x), j + u, 64);
                v[u] = __shfl(meta.y, j + u, 64);
            }
#pragma unroll
            for (int u = 0; u < 8; ++u)           // 8 independent gathers in flight
                g[u] = xk[(size_t)c[u] * HDIM + lane];
#pragma unroll
            for (int u = 0; u < 8; ++u)
                a[u] = fmaf(g[u], v[u], a[u]);
        }
        for (; j < cnt; ++j) {
            const int   cc = __shfl(__float_as_int(meta.x), j, 64);
            const float vv = __shfl(meta.y, j, 64);
            a[0] = fmaf(xk[(size_t)cc * HDIM + lane], vv, a[0]);
        }
    }

    float acc = ((a[0] + a[1]) + (a[2] + a[3])) + ((a[4] + a[5]) + (a[6] + a[7]));
    acc = fmaxf(acc, 0.f);

    __shared__ float sacc[4][HDIM];
    sacc[k][lane] = acc;
    __syncthreads();
    if (k == 0)      h0[(size_t)n * HDIM + lane] = sacc[0][lane] + sacc[1][lane];
    else if (k == 1) h1[(size_t)n * HDIM + lane] = sacc[2][lane] + sacc[3][lane];
}

// ---------------------------------------------------------------------------
// Stages 2-4: aggregate-then-transform.  spmm(x@W) == spmm(x)@W, so gather the
// *input* h0/h1 (25.6 MB working set -> L2-resident) and apply W afterwards.
// agg[k][n][:] = sum_e v * xin_k[col[e]][:]
// ---------------------------------------------------------------------------
__global__ void agg_csr(const float2* __restrict__ srt,
                        const int*    __restrict__ row_ptr,
                        const float*  __restrict__ x0,
                        const float*  __restrict__ x1,
                        float* __restrict__ agg)    // [4][N][H]
{
    const int k = threadIdx.x >> 6;
    const int lane = threadIdx.x & 63;
    const int n = blockIdx.x;

    const int s  = row_ptr[k * NP1 + n];
    const int en = row_ptr[k * NP1 + n + 1];
    const float2* sp = srt + (size_t)k * E_ADJ;
    const float*  xk = (k & 1) ? x1 : x0;

    float a[8] = {0.f, 0.f, 0.f, 0.f, 0.f, 0.f, 0.f, 0.f};

    for (int base = s; base < en; base += 64) {
        const int cnt = min(64, en - base);
        float2 meta = make_float2(0.f, 0.f);
        if (lane < cnt) meta = ntl_f2(&sp[base + lane]);

        int j = 0;
        for (; j + 8 <= cnt; j += 8) {
            int   c[8];
            float v[8], g[8];
#pragma unroll
            for (int u = 0; u < 8; ++u) {
                c[u] = __shfl(__float_as_int(meta.x), j + u, 64);
                v[u] = __shfl(meta.y, j + u, 64);
            }
#pragma unroll
            for (int u = 0; u < 8; ++u)
                g[u] = xk[(size_t)c[u] * HDIM + lane];
#pragma unroll
            for (int u = 0; u < 8; ++u)
                a[u] = fmaf(g[u], v[u], a[u]);
        }
        for (; j < cnt; ++j) {
            const int   cc = __shfl(__float_as_int(meta.x), j, 64);
            const float vv = __shfl(meta.y, j, 64);
            a[0] = fmaf(xk[(size_t)cc * HDIM + lane], vv, a[0]);
        }
    }

    const float acc = ((a[0] + a[1]) + (a[2] + a[3])) + ((a[4] + a[5]) + (a[6] + a[7]));
    // NT store: agg is consumed once, sequentially, by gemm2 — keep L2 for gathers
    nts_f(&agg[((size_t)k * N_NODES + n) * HDIM + lane], acc);
}

// y_k = relu(agg_k @ W_k); h0 = y0+y1, h1 = y2+y3.  8 nodes/block, wave = k.
__global__ void gemm2(const float* __restrict__ agg,  // [4][N][H]
                      const float* __restrict__ W,    // [4][H][H]
                      float* __restrict__ h0, float* __restrict__ h1)
{
    const int wave = threadIdx.x >> 6;   // relation k
    const int lane = threadIdx.x & 63;   // h
    const int n0 = blockIdx.x * 8;       // 6250 blocks

    __shared__ float sg[4][8][HDIM];
    for (int i = threadIdx.x; i < 4 * 8 * HDIM; i += 256) {
        const int k = i >> 9, rem = i & 511;
        const int r = rem >> 6, f = rem & 63;
        sg[k][r][f] = ntl_f(&agg[((size_t)k * N_NODES + n0 + r) * HDIM + f]);
    }
    __syncthreads();

    const float* Wk = W + (size_t)wave * HDIM * HDIM;
    float acc[8] = {0.f, 0.f, 0.f, 0.f, 0.f, 0.f, 0.f, 0.f};
#pragma unroll 4
    for (int f = 0; f < HDIM; ++f) {
        const float w = Wk[f * HDIM + lane];
#pragma unroll
        for (int r = 0; r < 8; ++r)
            acc[r] = fmaf(sg[wave][r][f], w, acc[r]);
    }
    __syncthreads();
#pragma unroll
    for (int r = 0; r < 8; ++r)
        sg[wave][r][lane] = fmaxf(acc[r], 0.f);   // reuse LDS for relu'd y
    __syncthreads();

    if (wave == 0) {
#pragma unroll
        for (int r = 0; r < 8; ++r)
            h0[(size_t)(n0 + r) * HDIM + lane] = sg[0][r][lane] + sg[1][r][lane];
    } else if (wave == 1) {
#pragma unroll
        for (int r = 0; r < 8; ++r)
            h1[(size_t)(n0 + r) * HDIM + lane] = sg[2][r][lane] + sg[3][r][lane];
    }
}

// ---------------------------------------------------------------------------
__global__ void make_M(const float* __restrict__ R, const float* __restrict__ Dl,
                       const int* __restrict__ rt_k, float* __restrict__ M)
{
    const int i = blockIdx.x * blockDim.x + threadIdx.x;
    if (i >= HDIM * HDIM) return;
    const float* d = Dl + rt_k[0] * HDIM;
    M[i] = d[i >> 6] * R[i] * d[i & 63];
}

// A[n][g] = sum_h h0[n][h] * M[h][g]   (16 rows/block, 4 waves x 4 rows)
__global__ void h0M_kernel(const float* __restrict__ h0, const float* __restrict__ M,
                           float* __restrict__ A)
{
    const int wave = threadIdx.x >> 6, lane = threadIdx.x & 63;
    const int n0 = blockIdx.x * 16;      // 3125 blocks * 16 = 50000 exactly

    __shared__ float sx[16][HDIM];
    for (int i = threadIdx.x; i < 16 * HDIM; i += 256)
        sx[i >> 6][i & 63] = h0[(size_t)n0 * HDIM + i];
    __syncthreads();

    float acc[4] = {0.f, 0.f, 0.f, 0.f};
#pragma unroll 4
    for (int f = 0; f < HDIM; ++f) {
        const float w = M[f * HDIM + lane];
#pragma unroll
        for (int r = 0; r < 4; ++r)
            acc[r] = fmaf(sx[wave * 4 + r][f], w, acc[r]);
    }
#pragma unroll
    for (int r = 0; r < 4; ++r)
        A[(size_t)(n0 + wave * 4 + r) * HDIM + lane] = acc[r];
}

// preds[e] = dot(A[i], h1[j]) — one wave per edge, 64-wide dot + reduce.
__global__ void decode(const float* __restrict__ A, const float* __restrict__ h1,
                       const int* __restrict__ edges, float* __restrict__ out)
{
    const long long t = (long long)blockIdx.x * 256 + threadIdx.x;
    const int e = (int)(t >> 6);
    const int lane = (int)(t & 63);

    const int i = edges[2 * (size_t)e];
    const int j = edges[2 * (size_t)e + 1];

    float p = A[(size_t)i * HDIM + lane] * h1[(size_t)j * HDIM + lane];
#pragma unroll
    for (int off = 32; off; off >>= 1)
        p += __shfl_down(p, off, 64);
    if (lane == 0) out[e] = p;
}

// ---------------------------------------------------------------------------
static void build_csr(const int* rows, const int* cols, const float* vals,
                      int* counts, int* row_ptr, int* blksums, int* wcur,
                      float2* srt, hipStream_t stream)
{
    hipMemsetAsync(counts, 0, 4 * N_NODES * sizeof(int), stream);
    const dim3 eg(E_ADJ / 256, 4);
    const dim3 sg(SCAN_NB, 4);
    hist_kernel<<<eg, 256, 0, stream>>>(rows, counts);
    scan1<<<sg, 256, 0, stream>>>(counts, row_ptr, blksums);
    scan2<<<1, 256, 0, stream>>>(blksums);
    scan3<<<sg, 256, 0, stream>>>(row_ptr, blksums, wcur);
    scatter_kernel<<<eg, 256, 0, stream>>>(rows, cols, vals, wcur, srt);
}

extern "C" void kernel_launch(void* const* d_in, const int* in_sizes, int n_in,
                              void* d_out, int out_size, void* d_ws, size_t ws_size,
                              hipStream_t stream) {
    const int*   adj_rows = (const int*)  d_in[0];
    const int*   adj_cols = (const int*)  d_in[1];
    const float* adj_vals = (const float*)d_in[2];
    const float* feat0    = (const float*)d_in[3];
    const float* feat1    = (const float*)d_in[4];
    const float* W1       = (const float*)d_in[5];
    const float* W2       = (const float*)d_in[6];
    const float* W3       = (const float*)d_in[7];
    const float* W4       = (const float*)d_in[8];
    const float* Rg       = (const float*)d_in[9];
    const float* Dl       = (const float*)d_in[10];
    const int*   edges    = (const int*)  d_in[11];
    const int*   rt_k     = (const int*)  d_in[12];
    float* out = (float*)d_out;

    const size_t NH = (size_t)N_NODES * HDIM;
    float* ws = (float*)d_ws;
    float*  xw      = ws;                         // 4*NH (stage-1 xw, agg buf, A)
    float*  h0      = xw + 4 * NH;                // NH
    float*  h1      = h0 + NH;                    // NH
    float2* srt     = (float2*)(h1 + NH);         // 4*E float2
    int*    row_ptr = (int*)(h1 + NH + 8 * (size_t)E_ADJ); // 4*(N+1)
    int*    wcur    = row_ptr + 4 * NP1 + 60;     // pad; 4*N
    int*    counts  = wcur + 4 * N_NODES;         // 4*N
    int*    blksums = counts + 4 * N_NODES;       // 4*SCAN_NB
    float*  M       = (float*)(blksums + 4 * SCAN_NB + 48); // 4096 f
    // total ~= 26.2M floats ~= 105 MB

    const int* r2 = adj_rows + 4 * (size_t)E_ADJ;
    const int* c2 = adj_cols + 4 * (size_t)E_ADJ;
    const float* v2 = adj_vals + 4 * (size_t)E_ADJ;

    // ---- CSR for adjacency group A (stages 1 & 2) ----
    build_csr(adj_rows, adj_cols, adj_vals, counts, row_ptr, blksums, wcur, srt, stream);

    // ---- stage 1: transform-then-aggregate (F=128 -> gather 64-dim xw) ----
    gemm_stage<FDIM><<<N_NODES / 8, 256, 0, stream>>>(feat0, feat1, W1, xw);
    spmm_csr<<<N_NODES, 256, 0, stream>>>(srt, row_ptr, xw, h0, h1);

    // ---- stage 2: aggregate-then-transform ----
    agg_csr<<<N_NODES, 256, 0, stream>>>(srt, row_ptr, h0, h1, xw);
    gemm2<<<N_NODES / 8, 256, 0, stream>>>(xw, W2, h0, h1);

    // ---- CSR for adjacency group B (stages 3 & 4) ----
    build_csr(r2, c2, v2, counts, row_ptr, blksums, wcur, srt, stream);

    // ---- stage 3 ----
    agg_csr<<<N_NODES, 256, 0, stream>>>(srt, row_ptr, h0, h1, xw);
    gemm2<<<N_NODES / 8, 256, 0, stream>>>(xw, W3, h0, h1);

    // ---- stage 4 ----
    agg_csr<<<N_NODES, 256, 0, stream>>>(srt, row_ptr, h0, h1, xw);
    gemm2<<<N_NODES / 8, 256, 0, stream>>>(xw, W4, h0, h1);

    // ---- decode: M, A = h0@M (A aliases xw), dot per edge ----
    make_M<<<(HDIM * HDIM + 255) / 256, 256, 0, stream>>>(Rg, Dl, rt_k, M);
    float* A = xw;
    h0M_kernel<<<N_NODES / 16, 256, 0, stream>>>(h0, M, A);
    decode<<<E_DEC * HDIM / 256, 256, 0, stream>>>(A, h1, edges, out);
}